// Round 2
// baseline (410.501 us; speedup 1.0000x reference)
//
#include <hip/hip_runtime.h>
#include <stdint.h>

// Problem constants
#define NJ 192                    // N1
#define OUT_HALF 12582912         // B*HN*N1 = 4096*16*192

// LDS strides (elements). Row strides are multiples of 8 elems (16B) so
// ds_read_b128/write_b128 stay aligned.
#define XS 520                    // X tile (bf16): 64 x 520
#define WS1 72                    // W1 chunk (bf16): 256 x 72
#define WS2 40                    // W2 chunk (bf16): 512 x 40
#define HS 264                    // H tile (bf16): 64 x 264
#define OS 516                    // O tile (f32):  64 x 516 (overlay)

typedef __attribute__((ext_vector_type(4))) float f32x4;
typedef __attribute__((ext_vector_type(8))) short bf16x8;
typedef __attribute__((ext_vector_type(4))) short bf16x4;

__device__ __forceinline__ float bf2f(short u) {
    union { float f; uint32_t i; } c;
    c.i = ((uint32_t)(uint16_t)u) << 16;
    return c.f;
}
__device__ __forceinline__ short f2bf(float f) {
    union { float f; uint32_t i; } c;
    c.f = f;
    uint32_t x = c.i;
    uint32_t r = (x + 0x7fffu + ((x >> 16) & 1u)) >> 16;   // RNE
    return (short)(uint16_t)r;
}

// One block: 64 rows (= 4 batches x 16 heads). 4 waves, each owns a 16-row
// m-tile. Fused: scatter -> LN -> GEMM1(relu) -> GEMM2(sigmoid) -> gather.
// All global tensors are float32; MFMA operands are bf16 (converted on the
// fly), accumulation f32, output stored f32.
__global__ __launch_bounds__(256, 1)
void fused_mlp(const float* __restrict__ rgb,
               const float* __restrict__ tir,
               const int*  __restrict__ gidx,
               const float* __restrict__ ln_g,
               const float* __restrict__ ln_b,
               const float* __restrict__ W1,   // (256, 512) row-major f32
               const float* __restrict__ b1,   // (256)
               const float* __restrict__ W2,   // (512, 256) row-major f32
               const float* __restrict__ b2,   // (512)
               float* __restrict__ out)        // rgb half then tir half, f32
{
    // 141312-byte arena, manually aliased:
    //   sX (bf16) [0, 66560)  sW (bf16) [66560, 107520)  sH (bf16) [107520, 141312)
    //   sO (f32)  [0, 132096) -- overlay, used only after GEMM2 completes
    __shared__ __attribute__((aligned(16))) char arena[141312];
    short* sX = (short*)arena;
    short* sW = (short*)(arena + 66560);
    short* sH = (short*)(arena + 107520);
    float* sO = (float*)arena;

    const int tid  = threadIdx.x;
    const int blk  = blockIdx.x;
    const int row0 = blk * 64;       // global row = b*16 + h
    const int b0   = blk * 4;
    const int wave = tid >> 6;
    const int lane = tid & 63;
    const int lr   = lane & 15;      // fragment row (A) / col (B,D)
    const int quad = lane >> 4;      // 0..3

    // ---- Phase 0: zero X, then scatter f32->bf16 through gidx ----
    {
        uint32_t* xz = (uint32_t*)sX;
        #pragma unroll
        for (int i = 0; i < 65; ++i) xz[tid + i * 256] = 0u;  // 65*256 dwords = 64*520 shorts
    }
    __syncthreads();
    for (int it = 0; it < 48; ++it) {
        int p = it * 256 + tid;           // 0 .. 64*192-1
        int r = p / NJ;
        int j = p - r * NJ;
        int iv = gidx[(b0 + (r >> 4)) * NJ + j];     // 0..255
        float vr = rgb[(row0 + r) * NJ + j];
        float vt = tir[(row0 + r) * NJ + j];
        sX[r * XS + iv]       = f2bf(vr);
        sX[r * XS + 256 + iv] = f2bf(vt);
    }
    __syncthreads();

    // ---- Phase 0.5: LayerNorm over 512 per row; 4 threads per row ----
    {
        int r = tid >> 2, sub = tid & 3;
        short* xr = sX + r * XS + sub * 128;
        float s = 0.f, ss = 0.f;
        #pragma unroll
        for (int t = 0; t < 16; ++t) {
            bf16x8 v8 = *(bf16x8*)(xr + t * 8);
            #pragma unroll
            for (int e = 0; e < 8; ++e) { float v = bf2f(v8[e]); s += v; ss += v * v; }
        }
        s  += __shfl_xor(s, 1, 64);  ss += __shfl_xor(ss, 1, 64);
        s  += __shfl_xor(s, 2, 64);  ss += __shfl_xor(ss, 2, 64);
        float mu  = s * (1.f / 512.f);
        float var = ss * (1.f / 512.f) - mu * mu;
        float rs  = rsqrtf(var + 1e-5f);
        const float* gp = ln_g + sub * 128;
        const float* bp = ln_b + sub * 128;
        #pragma unroll
        for (int t = 0; t < 16; ++t) {
            bf16x8 v8 = *(bf16x8*)(xr + t * 8);
            f32x4 g0 = *(const f32x4*)(gp + t * 8);
            f32x4 g1 = *(const f32x4*)(gp + t * 8 + 4);
            f32x4 b0v = *(const f32x4*)(bp + t * 8);
            f32x4 b1v = *(const f32x4*)(bp + t * 8 + 4);
            bf16x8 o8;
            #pragma unroll
            for (int e = 0; e < 4; ++e) {
                o8[e]     = f2bf((bf2f(v8[e])     - mu) * rs * g0[e] + b0v[e]);
                o8[e + 4] = f2bf((bf2f(v8[e + 4]) - mu) * rs * g1[e] + b1v[e]);
            }
            *(bf16x8*)(xr + t * 8) = o8;
        }
    }
    __syncthreads();

    // ---- Phase 1: H(64x256) = relu(X @ W1^T + b1), K=512 in chunks of 64 ----
    f32x4 acc1[16];
    #pragma unroll
    for (int i = 0; i < 16; ++i) acc1[i] = (f32x4){0.f, 0.f, 0.f, 0.f};

    for (int k0 = 0; k0 < 512; k0 += 64) {
        {   // stage W1[:, k0:k0+64) f32->bf16: 16 lanes/row-segment, 16 rows/iter
            int col4 = (tid & 15) * 4;
            int rb   = tid >> 4;
            #pragma unroll
            for (int i = 0; i < 16; ++i) {
                int row = rb + i * 16;
                f32x4 w = *(const f32x4*)(W1 + row * 512 + k0 + col4);
                bf16x4 o; 
                #pragma unroll
                for (int e = 0; e < 4; ++e) o[e] = f2bf(w[e]);
                *(bf16x4*)(sW + row * WS1 + col4) = o;
            }
        }
        __syncthreads();
        #pragma unroll
        for (int kk = 0; kk < 64; kk += 32) {
            bf16x8 a = *(const bf16x8*)(sX + (wave * 16 + lr) * XS + k0 + kk + quad * 8);
            #pragma unroll
            for (int nt = 0; nt < 16; ++nt) {
                bf16x8 bfr = *(const bf16x8*)(sW + (nt * 16 + lr) * WS1 + kk + quad * 8);
                acc1[nt] = __builtin_amdgcn_mfma_f32_16x16x32_bf16(a, bfr, acc1[nt], 0, 0, 0);
            }
        }
        __syncthreads();   // sW reused next chunk
    }

    // epilogue 1: bias + relu -> bf16 H in LDS (C/D layout: col=lr, row=quad*4+rr)
    #pragma unroll
    for (int nt = 0; nt < 16; ++nt) {
        int col = nt * 16 + lr;
        float bias = b1[col];
        #pragma unroll
        for (int rr = 0; rr < 4; ++rr) {
            int row = wave * 16 + quad * 4 + rr;
            float h = acc1[nt][rr] + bias;
            sH[row * HS + col] = f2bf(fmaxf(h, 0.f));
        }
    }
    __syncthreads();

    // ---- Phase 2: O(64x512) = sigmoid(H @ W2^T + b2), K=256 in chunks of 32 ----
    f32x4 acc2[32];
    #pragma unroll
    for (int i = 0; i < 32; ++i) acc2[i] = (f32x4){0.f, 0.f, 0.f, 0.f};

    for (int k0 = 0; k0 < 256; k0 += 32) {
        {   // stage W2[:, k0:k0+32) f32->bf16: 8 lanes/row-segment, 32 rows/iter
            int col4 = (tid & 7) * 4;
            int rb   = tid >> 3;
            #pragma unroll
            for (int i = 0; i < 16; ++i) {
                int row = rb + i * 32;
                f32x4 w = *(const f32x4*)(W2 + row * 256 + k0 + col4);
                bf16x4 o;
                #pragma unroll
                for (int e = 0; e < 4; ++e) o[e] = f2bf(w[e]);
                *(bf16x4*)(sW + row * WS2 + col4) = o;
            }
        }
        __syncthreads();
        bf16x8 a = *(const bf16x8*)(sH + (wave * 16 + lr) * HS + k0 + quad * 8);
        #pragma unroll
        for (int nt = 0; nt < 32; ++nt) {
            bf16x8 bfr = *(const bf16x8*)(sW + (nt * 16 + lr) * WS2 + quad * 8);
            acc2[nt] = __builtin_amdgcn_mfma_f32_16x16x32_bf16(a, bfr, acc2[nt], 0, 0, 0);
        }
        __syncthreads();
    }

    // epilogue 2: bias + sigmoid -> f32 O (overlays the whole arena; X/W/H dead)
    #pragma unroll
    for (int nt = 0; nt < 32; ++nt) {
        int col = nt * 16 + lr;
        float bias = b2[col];
        #pragma unroll
        for (int rr = 0; rr < 4; ++rr) {
            int row = wave * 16 + quad * 4 + rr;
            float x = acc2[nt][rr] + bias;
            float sg = 1.f / (1.f + __expf(-x));
            sO[row * OS + col] = sg;
        }
    }
    __syncthreads();

    // ---- Phase 3: gather through gidx and store both halves (f32) ----
    for (int it = 0; it < 48; ++it) {
        int p = it * 256 + tid;
        int r = p / NJ;
        int j = p - r * NJ;
        int iv = gidx[(b0 + (r >> 4)) * NJ + j];
        out[(row0 + r) * NJ + j]            = sO[r * OS + iv];
        out[OUT_HALF + (row0 + r) * NJ + j] = sO[r * OS + 256 + iv];
    }
}

extern "C" void kernel_launch(void* const* d_in, const int* in_sizes, int n_in,
                              void* d_out, int out_size, void* d_ws, size_t ws_size,
                              hipStream_t stream) {
    const float* rgb  = (const float*)d_in[0];
    const float* tir  = (const float*)d_in[1];
    const int*   gidx = (const int*)d_in[2];
    const float* ln_g = (const float*)d_in[3];
    const float* ln_b = (const float*)d_in[4];
    const float* W1   = (const float*)d_in[5];
    const float* b1   = (const float*)d_in[6];
    const float* W2   = (const float*)d_in[7];
    const float* b2   = (const float*)d_in[8];
    float* out = (float*)d_out;

    // 65536 rows / 64 rows per block
    fused_mlp<<<1024, 256, 0, stream>>>(rgb, tir, gidx, ln_g, ln_b, W1, b1, W2, b2, out);
}

// Round 4
// 351.170 us; speedup vs baseline: 1.1690x; 1.1690x over previous
//
#include <hip/hip_runtime.h>
#include <stdint.h>

// Problem constants
#define NJ 192                    // N1
#define OUT_HALF 12582912         // B*HN*N1 = 4096*16*192

// LDS strides (elements). Row strides are multiples of 8 elems (16B) so
// ds_read_b128/write_b128 stay aligned; stride mod 32 dwords = 4 gives a
// 4-bank shift per row -> fragment reads are 2-way aliased (free on CDNA4).
#define XS 520                    // X tile (bf16): 64 x 520
#define WS1 72                    // W1 chunk (bf16): 256 x 72
#define WS2 40                    // W2 chunk (bf16): 512 x 40
#define HS 264                    // H tile (bf16): 64 x 264
#define OS 516                    // O tile (f32):  64 x 516 (overlay)

typedef __attribute__((ext_vector_type(4))) float f32x4;
typedef __attribute__((ext_vector_type(8))) short bf16x8;

__device__ __forceinline__ float bf2f(short u) {
    union { float f; uint32_t i; } c;
    c.i = ((uint32_t)(uint16_t)u) << 16;
    return c.f;
}
__device__ __forceinline__ short f2bf(float f) {
    union { float f; uint32_t i; } c;
    c.f = f;
    uint32_t x = c.i;
    uint32_t r = (x + 0x7fffu + ((x >> 16) & 1u)) >> 16;   // RNE
    return (short)(uint16_t)r;
}

// ---------------------------------------------------------------------------
// Pre-kernel: convert W1/W2 f32 -> bf16, packed chunk-major into d_ws so the
// main kernel's staging is pure contiguous bf16x8 copies (no VALU convert).
//   P1 (at ws+0):      8 chunks of K=64:  (c<8, row<256) blocks: c*2048 + row*8 + j
//   P2 (at ws+131072): 8 chunks of K=32:  (c<8, row<512) blocks: c*2048 + row*4 + j
// 32768 threads, one 8-elem block each.
// ---------------------------------------------------------------------------
__global__ __launch_bounds__(256)
void pack_weights(const float* __restrict__ W1, const float* __restrict__ W2,
                  short* __restrict__ ws) {
    int id = blockIdx.x * 256 + threadIdx.x;     // 0..32767
    const float* src;
    short* dst;
    if (id < 16384) {              // W1: 2048 blocks per chunk, 8 chunks
        int c = id >> 11, w = id & 2047;
        int row = w >> 3, j = w & 7;
        src = W1 + row * 512 + c * 64 + j * 8;
        dst = ws + id * 8;
    } else {                       // W2: 2048 blocks per chunk, 8 chunks
        int id2 = id - 16384;
        int c = id2 >> 11, w = id2 & 2047;
        int row = w >> 2, j = w & 3;
        src = W2 + row * 256 + c * 32 + j * 8;
        dst = ws + 131072 + id2 * 8;
    }
    f32x4 a = *(const f32x4*)src;
    f32x4 b = *(const f32x4*)(src + 4);
    bf16x8 o;
    #pragma unroll
    for (int e = 0; e < 4; ++e) { o[e] = f2bf(a[e]); o[e + 4] = f2bf(b[e]); }
    *(bf16x8*)dst = o;
}

// ---------------------------------------------------------------------------
// Main kernel. One block: 64 rows (4 batches x 16 heads), 1024 threads =
// 16 waves = (4 m-tiles) x (4 N-quarters). Fused scatter -> LN -> GEMM1(relu)
// -> GEMM2(sigmoid) -> gather. 141312 B LDS -> 1 block/CU, 4 waves/SIMD.
// ---------------------------------------------------------------------------
__global__ __launch_bounds__(1024)
void fused_mlp(const float* __restrict__ rgb,
               const float* __restrict__ tir,
               const int*  __restrict__ gidx,
               const float* __restrict__ ln_g,
               const float* __restrict__ ln_b,
               const short* __restrict__ P1,   // packed bf16 W1 chunks
               const float* __restrict__ b1,   // (256)
               const short* __restrict__ P2,   // packed bf16 W2 chunks
               const float* __restrict__ b2,   // (512)
               float* __restrict__ out)        // rgb half then tir half, f32
{
    // 141312-byte arena, manually aliased:
    //   sX (bf16) [0, 66560)  sW (bf16) [66560, 107520)  sH (bf16) [107520, 141312)
    //   sO (f32)  [0, 132096) -- overlay, used only after GEMM2 completes
    __shared__ __attribute__((aligned(16))) char arena[141312];
    short* sX = (short*)arena;
    short* sW = (short*)(arena + 66560);
    short* sH = (short*)(arena + 107520);
    float* sO = (float*)arena;

    const int tid  = threadIdx.x;
    const int blk  = blockIdx.x;
    const int row0 = blk * 64;       // global row = b*16 + h
    const int b0   = blk * 4;
    const int wave = tid >> 6;
    const int lane = tid & 63;
    const int lr   = lane & 15;      // fragment row (A) / col (B,D)
    const int quad = lane >> 4;      // 0..3
    const int mw   = wave & 3;       // m-tile (16 rows)
    const int nw   = wave >> 2;      // N-quarter

    // ---- Phase 0: zero X, then scatter f32->bf16 through gidx ----
    {
        uint32_t* xz = (uint32_t*)sX;
        for (int i = tid; i < 16640; i += 1024) xz[i] = 0u;   // 64*520 shorts
    }
    __syncthreads();
    #pragma unroll
    for (int it = 0; it < 12; ++it) {
        int p = it * 1024 + tid;          // 0 .. 64*192-1
        int r = p / NJ;
        int j = p - r * NJ;
        int iv = gidx[(b0 + (r >> 4)) * NJ + j];     // 0..255
        float vr = rgb[(row0 + r) * NJ + j];
        float vt = tir[(row0 + r) * NJ + j];
        sX[r * XS + iv]       = f2bf(vr);
        sX[r * XS + 256 + iv] = f2bf(vt);
    }
    __syncthreads();

    // ---- Phase 0.5: LayerNorm over 512 per row; 16 threads per row ----
    {
        int r = tid >> 4, sub = tid & 15;
        short* xr = sX + r * XS + sub * 32;
        float s = 0.f, ss = 0.f;
        #pragma unroll
        for (int t = 0; t < 4; ++t) {
            bf16x8 v8 = *(bf16x8*)(xr + t * 8);
            #pragma unroll
            for (int e = 0; e < 8; ++e) { float v = bf2f(v8[e]); s += v; ss += v * v; }
        }
        s  += __shfl_xor(s, 1, 16);  ss += __shfl_xor(ss, 1, 16);
        s  += __shfl_xor(s, 2, 16);  ss += __shfl_xor(ss, 2, 16);
        s  += __shfl_xor(s, 4, 16);  ss += __shfl_xor(ss, 4, 16);
        s  += __shfl_xor(s, 8, 16);  ss += __shfl_xor(ss, 8, 16);
        float mu  = s * (1.f / 512.f);
        float var = ss * (1.f / 512.f) - mu * mu;
        float rs  = rsqrtf(var + 1e-5f);
        const float* gp = ln_g + sub * 32;
        const float* bp = ln_b + sub * 32;
        #pragma unroll
        for (int t = 0; t < 4; ++t) {
            bf16x8 v8 = *(bf16x8*)(xr + t * 8);
            f32x4 g0 = *(const f32x4*)(gp + t * 8);
            f32x4 g1 = *(const f32x4*)(gp + t * 8 + 4);
            f32x4 c0 = *(const f32x4*)(bp + t * 8);
            f32x4 c1 = *(const f32x4*)(bp + t * 8 + 4);
            bf16x8 o8;
            #pragma unroll
            for (int e = 0; e < 4; ++e) {
                o8[e]     = f2bf((bf2f(v8[e])     - mu) * rs * g0[e] + c0[e]);
                o8[e + 4] = f2bf((bf2f(v8[e + 4]) - mu) * rs * g1[e] + c1[e]);
            }
            *(bf16x8*)(xr + t * 8) = o8;
        }
    }
    __syncthreads();

    // ---- Phase 1: H(64x256) = relu(X @ W1^T + b1), K=512 in 8 chunks of 64 ----
    f32x4 acc1[4];
    #pragma unroll
    for (int i = 0; i < 4; ++i) acc1[i] = (f32x4){0.f, 0.f, 0.f, 0.f};

    for (int c = 0; c < 8; ++c) {
        {   // stage chunk: 2048 bf16x8 blocks, 2 per thread (already bf16!)
            const short* src = P1 + c * 16384;
            #pragma unroll
            for (int i = 0; i < 2; ++i) {
                int idx = i * 1024 + tid;         // 8-elem block index
                int row = idx >> 3, j = idx & 7;
                *(bf16x8*)(sW + row * WS1 + j * 8) = *(const bf16x8*)(src + idx * 8);
            }
        }
        __syncthreads();
        #pragma unroll
        for (int kk = 0; kk < 64; kk += 32) {
            bf16x8 a = *(const bf16x8*)(sX + (mw * 16 + lr) * XS + c * 64 + kk + quad * 8);
            #pragma unroll
            for (int i = 0; i < 4; ++i) {
                int nt = nw * 4 + i;
                bf16x8 bfr = *(const bf16x8*)(sW + (nt * 16 + lr) * WS1 + kk + quad * 8);
                acc1[i] = __builtin_amdgcn_mfma_f32_16x16x32_bf16(a, bfr, acc1[i], 0, 0, 0);
            }
        }
        __syncthreads();   // sW reused next chunk
    }

    // epilogue 1: bias + relu -> bf16 H in LDS (C/D layout: col=lr, row=quad*4+rr)
    #pragma unroll
    for (int i = 0; i < 4; ++i) {
        int col = (nw * 4 + i) * 16 + lr;
        float bias = b1[col];
        #pragma unroll
        for (int rr = 0; rr < 4; ++rr) {
            int row = mw * 16 + quad * 4 + rr;
            float h = acc1[i][rr] + bias;
            sH[row * HS + col] = f2bf(fmaxf(h, 0.f));
        }
    }
    __syncthreads();

    // ---- Phase 2: O(64x512) = sigmoid(H @ W2^T + b2), K=256 in 8 chunks of 32 ----
    f32x4 acc2[8];
    #pragma unroll
    for (int i = 0; i < 8; ++i) acc2[i] = (f32x4){0.f, 0.f, 0.f, 0.f};

    for (int c = 0; c < 8; ++c) {
        {   // stage chunk: 2048 bf16x8 blocks, 2 per thread
            const short* src = P2 + c * 16384;
            #pragma unroll
            for (int i = 0; i < 2; ++i) {
                int idx = i * 1024 + tid;
                int row = idx >> 2, j = idx & 3;
                *(bf16x8*)(sW + row * WS2 + j * 8) = *(const bf16x8*)(src + idx * 8);
            }
        }
        __syncthreads();
        bf16x8 a = *(const bf16x8*)(sH + (mw * 16 + lr) * HS + c * 32 + quad * 8);
        #pragma unroll
        for (int i = 0; i < 8; ++i) {
            int nt = nw * 8 + i;
            bf16x8 bfr = *(const bf16x8*)(sW + (nt * 16 + lr) * WS2 + quad * 8);
            acc2[i] = __builtin_amdgcn_mfma_f32_16x16x32_bf16(a, bfr, acc2[i], 0, 0, 0);
        }
        __syncthreads();
    }

    // epilogue 2: bias + sigmoid -> f32 O (overlays the arena; X/W/H dead)
    #pragma unroll
    for (int i = 0; i < 8; ++i) {
        int col = (nw * 8 + i) * 16 + lr;
        float bias = b2[col];
        #pragma unroll
        for (int rr = 0; rr < 4; ++rr) {
            int row = mw * 16 + quad * 4 + rr;
            float x = acc2[i][rr] + bias;
            float sg = 1.f / (1.f + __expf(-x));
            sO[row * OS + col] = sg;
        }
    }
    __syncthreads();

    // ---- Phase 3: gather through gidx and store both halves (f32) ----
    #pragma unroll
    for (int it = 0; it < 12; ++it) {
        int p = it * 1024 + tid;
        int r = p / NJ;
        int j = p - r * NJ;
        int iv = gidx[(b0 + (r >> 4)) * NJ + j];
        out[(row0 + r) * NJ + j]            = sO[r * OS + iv];
        out[OUT_HALF + (row0 + r) * NJ + j] = sO[r * OS + 256 + iv];
    }
}

extern "C" void kernel_launch(void* const* d_in, const int* in_sizes, int n_in,
                              void* d_out, int out_size, void* d_ws, size_t ws_size,
                              hipStream_t stream) {
    const float* rgb  = (const float*)d_in[0];
    const float* tir  = (const float*)d_in[1];
    const int*   gidx = (const int*)d_in[2];
    const float* ln_g = (const float*)d_in[3];
    const float* ln_b = (const float*)d_in[4];
    const float* W1   = (const float*)d_in[5];
    const float* b1   = (const float*)d_in[6];
    const float* W2   = (const float*)d_in[7];
    const float* b2   = (const float*)d_in[8];
    float* out = (float*)d_out;
    short* wsp = (short*)d_ws;     // needs 512 KB: P1 at 0, P2 at elem 131072

    pack_weights<<<128, 256, 0, stream>>>(W1, W2, wsp);
    fused_mlp<<<1024, 1024, 0, stream>>>(rgb, tir, gidx, ln_g, ln_b,
                                         wsp, b1, wsp + 131072, b2, out);
}